// Round 4
// baseline (192.277 us; speedup 1.0000x reference)
//
#include <hip/hip_runtime.h>

// Scatter rows of `in` (B x TRIU_LEN) into upper triangle of out (B x N x N).
// triu row-major: row i starts at input offset i*N - i*(i-1)/2.
// Memory-bound: 256 MiB read + 512 MiB write -> ~122 us floor @ 6.3 TB/s.
//
// Round-3 lesson: 1 outstanding load/wave (load->wait->store loop) is
// latency-limited (~22 KB/CU in flight needed at 900cy HBM latency).
// Fix: each wave owns 256 consecutive quads (= half an output row) and
// issues 4 independent 1KB wave-loads before the 4 stores -> 4x MLP.
//
// Row geometry: a wave's 256 quads sit inside ONE row (512 quads/row),
// so row index i is wave-uniform; divergence only in the straddle wave.

#define MATSIZE 2048
#define TRIU_LEN 2098176  // 2048*2049/2

typedef float vf4 __attribute__((ext_vector_type(4)));

__device__ __forceinline__ vf4 nt_load(const float* p) {
    return __builtin_nontemporal_load(reinterpret_cast<const vf4*>(p));
}
__device__ __forceinline__ void nt_store(vf4 v, vf4* p) {
    __builtin_nontemporal_store(v, p);
}

__global__ __launch_bounds__(256) void triu_scatter_kernel(
    const float* __restrict__ in, float* __restrict__ out) {
    const int tid  = blockIdx.x * blockDim.x + threadIdx.x;
    const int lane = tid & 63;
    const int wave = tid >> 6;                 // 0..8191 (2048 blocks x 4 waves)
    for (int pass = 0; pass < 16; ++pass) {
        // global chunk of 256 quads for this wave this pass
        const int q0  = ((pass << 13) + wave) * 256 + lane;   // + k*64, k=0..3
        const int b   = q0 >> 20;              // 2^20 quads per matrix
        const int rem = q0 & ((1 << 20) - 1);
        const int i   = rem >> 9;              // row (wave-uniform)
        const int j0  = (rem & 511) << 2;      // col of quad k=0; j_k = j0+256k
        const int row_off = i * MATSIZE - (i * (i - 1)) / 2;
        const float* src = in + (size_t)b * TRIU_LEN + row_off;
        vf4* dst = reinterpret_cast<vf4*>(out) + q0;

        if (j0 >= i) {
            // all 4 chunks fully inside the triangle: 4 independent loads
            const float* p = src + (j0 - i);
            vf4 v0 = nt_load(p);
            vf4 v1 = nt_load(p + 256);
            vf4 v2 = nt_load(p + 512);
            vf4 v3 = nt_load(p + 768);
            nt_store(v0, dst);
            nt_store(v1, dst + 64);
            nt_store(v2, dst + 128);
            nt_store(v3, dst + 192);
        } else if (j0 + 768 + 3 < i) {
            // all 4 chunks strictly below the diagonal
            vf4 z = (vf4){0.f, 0.f, 0.f, 0.f};
            nt_store(z, dst);
            nt_store(z, dst + 64);
            nt_store(z, dst + 128);
            nt_store(z, dst + 192);
        } else {
            // diagonal crosses this wave's span: per-chunk 3-way
            #pragma unroll
            for (int k = 0; k < 4; ++k) {
                const int jk = j0 + (k << 8);
                vf4 v;
                if (jk >= i) {
                    v = nt_load(src + (jk - i));
                } else if (jk + 3 < i) {
                    v = (vf4){0.f, 0.f, 0.f, 0.f};
                } else {
                    v.x = (jk + 0 >= i) ? src[jk + 0 - i] : 0.f;
                    v.y = (jk + 1 >= i) ? src[jk + 1 - i] : 0.f;
                    v.z = (jk + 2 >= i) ? src[jk + 2 - i] : 0.f;
                    v.w = (jk + 3 >= i) ? src[jk + 3 - i] : 0.f;
                }
                nt_store(v, dst + (k << 6));
            }
        }
    }
}

extern "C" void kernel_launch(void* const* d_in, const int* in_sizes, int n_in,
                              void* d_out, int out_size, void* d_ws, size_t ws_size,
                              hipStream_t stream) {
    const float* in = (const float*)d_in[0];
    float* out = (float*)d_out;
    const int block = 256;
    const int grid = 2048;   // 8192 waves; 16 passes x 256 quads/wave = 2^25 quads
    triu_scatter_kernel<<<grid, block, 0, stream>>>(in, out);
}

// Round 5
// 141.770 us; speedup vs baseline: 1.3563x; 1.3563x over previous
//
#include <hip/hip_runtime.h>

// Scatter rows of `in` (B x TRIU_LEN) into upper triangle of out (B x N x N).
// Round-5 theory: prior kernels at 4.3 TB/s were limited by DRAM page
// thrash from ~16K interleaved 1KB-granule streams (grid-stride, 8192
// waves). Fill kernel hits 6.7 TB/s with ~880 long sequential streams.
// => 1024 waves, each owning two contiguous 32-row slabs (top + mirrored
// bottom slab for uniform work/wave), walked sequentially; 8 batched
// loads per row for MLP; wave-uniform row => scalar branches only.

#define MATSIZE 2048
#define TRIU_LEN 2098176   // 2048*2049/2
#define SLAB 32            // rows per slab
#define NSLABS 2048        // 65536 rows / SLAB

typedef float vf4 __attribute__((ext_vector_type(4)));

__device__ __forceinline__ void do_row(const float* __restrict__ in,
                                       float* __restrict__ out,
                                       int R, int lane) {
    const int b = R >> 11;          // batch
    const int i = R & 2047;         // row in matrix (wave-uniform)
    const float* src = in + (size_t)b * TRIU_LEN
                          + i * MATSIZE - ((i * (i - 1)) >> 1);
    vf4* dst = reinterpret_cast<vf4*>(out) + ((size_t)R << 9);
    const int c0 = (i + 255) >> 8;  // first chunk fully inside triangle
    const int cd = i >> 8;          // chunk containing the diagonal
    vf4 v[8];
    #pragma unroll
    for (int c = 0; c < 8; ++c) {
        const int j = (c << 8) | (lane << 2);
        if (c >= c0) {
            // fully inside: 4B-aligned dwordx4 (HW-legal), exact row bytes
            v[c] = *reinterpret_cast<const vf4*>(src + (j - i));
        } else if (c == cd) {
            // diagonal straddle: clamped load stays inside `in`, then select
            vf4 w = *reinterpret_cast<const vf4*>(src + (j - i));
            w.x = (j + 0 >= i) ? w.x : 0.f;
            w.y = (j + 1 >= i) ? w.y : 0.f;
            w.z = (j + 2 >= i) ? w.z : 0.f;
            w.w = (j + 3 >= i) ? w.w : 0.f;
            v[c] = w;
        } else {
            v[c] = (vf4){0.f, 0.f, 0.f, 0.f};
        }
    }
    #pragma unroll
    for (int c = 0; c < 8; ++c) {
        __builtin_nontemporal_store(v[c], dst + (c << 6) + lane);
    }
}

__global__ __launch_bounds__(256) void triu_scatter_kernel(
    const float* __restrict__ in, float* __restrict__ out) {
    const int lane = threadIdx.x & 63;
    const int wave = (blockIdx.x << 2) | (threadIdx.x >> 6);   // 0..1023
    const int rA = wave * SLAB;                  // slab from the top
    const int rB = (NSLABS - 1 - wave) * SLAB;   // mirrored slab from bottom
    for (int r = 0; r < SLAB; ++r) {
        do_row(in, out, rA + r, lane);
        do_row(in, out, rB + r, lane);
    }
}

extern "C" void kernel_launch(void* const* d_in, const int* in_sizes, int n_in,
                              void* d_out, int out_size, void* d_ws, size_t ws_size,
                              hipStream_t stream) {
    const float* in = (const float*)d_in[0];
    float* out = (float*)d_out;
    // 256 blocks x 4 waves = 1024 waves; 2048 slabs, 2 per wave.
    triu_scatter_kernel<<<256, 256, 0, stream>>>(in, out);
}

// Round 6
// 126.669 us; speedup vs baseline: 1.5179x; 1.1192x over previous
//
#include <hip/hip_runtime.h>

// Scatter rows of `in` (B x TRIU_LEN) into upper triangle of out (B x N x N).
// Round-6: keep round-5's long-contiguous-stream structure (the +28% win),
// double wave parallelism: 2048 waves (8/CU), slab=16 rows, mirrored
// top/bottom slab pairing for uniform bytes/wave, and process slab A fully
// before slab B so each wave keeps only 2 concurrent streams (1R+1W).
// Total concurrent streams ~4096, same as round 5, with 2x the waves.

#define MATSIZE 2048
#define TRIU_LEN 2098176   // 2048*2049/2
#define SLAB 16            // rows per slab
#define NSLABS 4096        // 65536 rows / SLAB

typedef float vf4 __attribute__((ext_vector_type(4)));

__device__ __forceinline__ void do_row(const float* __restrict__ in,
                                       float* __restrict__ out,
                                       int R, int lane) {
    const int b = R >> 11;          // batch
    const int i = R & 2047;         // row in matrix (wave-uniform)
    const float* src = in + (size_t)b * TRIU_LEN
                          + i * MATSIZE - ((i * (i - 1)) >> 1);
    vf4* dst = reinterpret_cast<vf4*>(out) + ((size_t)R << 9);
    const int c0 = (i + 255) >> 8;  // first chunk fully inside triangle
    const int cd = i >> 8;          // chunk containing the diagonal
    vf4 v[8];
    #pragma unroll
    for (int c = 0; c < 8; ++c) {
        const int j = (c << 8) | (lane << 2);
        if (c >= c0) {
            // fully inside: 4B-aligned dwordx4 (HW-legal), exact row bytes
            v[c] = *reinterpret_cast<const vf4*>(src + (j - i));
        } else if (c == cd) {
            // diagonal straddle: clamped load stays inside `in`, then select
            vf4 w = *reinterpret_cast<const vf4*>(src + (j - i));
            w.x = (j + 0 >= i) ? w.x : 0.f;
            w.y = (j + 1 >= i) ? w.y : 0.f;
            w.z = (j + 2 >= i) ? w.z : 0.f;
            w.w = (j + 3 >= i) ? w.w : 0.f;
            v[c] = w;
        } else {
            v[c] = (vf4){0.f, 0.f, 0.f, 0.f};
        }
    }
    #pragma unroll
    for (int c = 0; c < 8; ++c) {
        __builtin_nontemporal_store(v[c], dst + (c << 6) + lane);
    }
}

__global__ __launch_bounds__(256) void triu_scatter_kernel(
    const float* __restrict__ in, float* __restrict__ out) {
    const int lane = threadIdx.x & 63;
    const int wave = (blockIdx.x << 2) | (threadIdx.x >> 6);   // 0..2047
    const int rA = wave * SLAB;                  // slab from the top
    const int rB = (NSLABS - 1 - wave) * SLAB;   // mirrored slab from bottom
    for (int r = 0; r < SLAB; ++r) do_row(in, out, rA + r, lane);
    for (int r = 0; r < SLAB; ++r) do_row(in, out, rB + r, lane);
}

extern "C" void kernel_launch(void* const* d_in, const int* in_sizes, int n_in,
                              void* d_out, int out_size, void* d_ws, size_t ws_size,
                              hipStream_t stream) {
    const float* in = (const float*)d_in[0];
    float* out = (float*)d_out;
    // 512 blocks x 4 waves = 2048 waves (8/CU); 4096 slabs, 2 per wave.
    triu_scatter_kernel<<<512, 256, 0, stream>>>(in, out);
}